// Round 8
// baseline (237.922 us; speedup 1.0000x reference)
//
#include <hip/hip_runtime.h>

#define VXC 0.2f
#define VYC 0.2f
#define XMINC -51.2f
#define YMINC -51.2f
#define GXD 512
#define GYD 512
#define NVOXD (GXD * GYD)   // 2^18
#define BN_EPS 1e-3f

// K0: zero the 4 MB count array (int4/thread, blocks [0, nzero)) and, in the
// extra last block, fold BN into the linear layer (P layout [9][64]).
__global__ void init_and_precompute(int* __restrict__ cnt, int nzero4,
                                    const float* __restrict__ W,
                                    const float* __restrict__ gamma,
                                    const float* __restrict__ beta,
                                    const float* __restrict__ mean,
                                    const float* __restrict__ var,
                                    float* __restrict__ P) {
    int nzero_blocks = (nzero4 + 255) / 256;
    if ((int)blockIdx.x < nzero_blocks) {
        int i = blockIdx.x * 256 + threadIdx.x;
        if (i < nzero4) ((int4*)cnt)[i] = make_int4(0, 0, 0, 0);
        return;
    }
    int c = threadIdx.x;
    if (c >= 64) return;
    float scale = gamma[c] * (1.0f / sqrtf(var[c] + BN_EPS));
    float w0 = W[0*64+c], w1 = W[1*64+c], w2 = W[2*64+c];
    float w3 = W[3*64+c], w4 = W[4*64+c], w5 = W[5*64+c];
    float w6 = W[6*64+c], w7 = W[7*64+c], w8 = W[8*64+c];
    P[0*64+c] = (w0 + w3 + w6) * scale;
    P[1*64+c] = (w1 + w4 + w7) * scale;
    P[2*64+c] = (w2 + w5 + w8) * scale;
    P[3*64+c] = w3 * scale;
    P[4*64+c] = w4 * scale;
    P[5*64+c] = w5 * scale;
    P[6*64+c] = w6 * scale;
    P[7*64+c] = w7 * scale;
    P[8*64+c] = beta[c] - mean[c] * scale;
}

// K1: 4 points per thread via 3x float4 loads; one scattered atomic per point;
// pack (vid, pos) into one uint; uint4 store of the 4 packed records.
__global__ void bin_points(const float* __restrict__ pc0, const float* __restrict__ pc1,
                           int* __restrict__ cnt, uint4* __restrict__ pk4,
                           int B, int N) {
    int i = blockIdx.x * blockDim.x + threadIdx.x;
    int per4 = (B * N) >> 2;                 // point-quads per cloud
    if (i >= 2 * per4) return;
    int cloud = (i >= per4) ? 1 : 0;
    int i2 = i - cloud * per4;               // quad id within cloud
    int b = i2 / (N >> 2);                   // N % 4 == 0 -> b uniform over the quad
    const float4* p4 = (const float4*)(cloud ? pc1 : pc0) + (size_t)i2 * 3;
    float4 q0 = p4[0], q1 = p4[1], q2 = p4[2];
    float xs[4] = {q0.x, q0.w, q1.z, q2.y};
    float ys[4] = {q0.y, q1.x, q1.w, q2.z};
    int vbase = (cloud * B + b) * NVOXD;
    unsigned r[4];
    #pragma unroll
    for (int k = 0; k < 4; ++k) {
        // Bit-exact with reference binning
        int ix = (int)floorf((xs[k] - XMINC) / VXC); ix = min(max(ix, 0), GXD - 1);
        int iy = (int)floorf((ys[k] - YMINC) / VYC); iy = min(max(iy, 0), GYD - 1);
        int hidx = vbase + ix * GYD + iy;
        int pos = atomicAdd(cnt + hidx, 1);
        r[k] = ((unsigned)hidx << 8) | (unsigned)pos;   // pos < 256 (lambda=0.38)
    }
    pk4[i] = make_uint4(r[0], r[1], r[2], r[3]);
}

// K2a/K2b: block-wise exclusive scan. 256 threads * int4 = 1024 elems/block.
__global__ void scan_block(const int* __restrict__ in, int* __restrict__ out,
                           int* __restrict__ bsums) {
    int tid = threadIdx.x;
    size_t base = (size_t)blockIdx.x * 1024;
    int4 v = ((const int4*)(in + base))[tid];
    int t0 = v.x, t1 = t0 + v.y, t2 = t1 + v.z, t3 = t2 + v.w;
    __shared__ int lds[256];
    lds[tid] = t3;
    __syncthreads();
    for (int d = 1; d < 256; d <<= 1) {
        int t = (tid >= d) ? lds[tid - d] : 0;
        __syncthreads();
        lds[tid] += t;
        __syncthreads();
    }
    int excl = lds[tid] - t3;
    if (tid == 255) bsums[blockIdx.x] = lds[255];
    ((int4*)(out + base))[tid] = make_int4(excl, excl + t0, excl + t1, excl + t2);
}

// K2c: add scanned block bases; write CSR sentinel off[n] = total.
__global__ void add_bases(int* __restrict__ off, const int* __restrict__ bases,
                          int n4, int total) {
    int i = blockIdx.x * blockDim.x + threadIdx.x;
    if (i >= n4) return;
    int4 v = ((int4*)off)[i];
    int b = bases[i >> 8];
    v.x += b; v.y += b; v.z += b; v.w += b;
    ((int4*)off)[i] = v;
    if (i == 0) off[n4 * 4] = total;
}

// K3: 4 points/thread; scattered plain float4 stores (no atomic) into CSR order.
__global__ void scatter_csr(const float* __restrict__ pc0, const float* __restrict__ pc1,
                            const int* __restrict__ off, const uint4* __restrict__ pk4,
                            float4* __restrict__ csr, int B, int N) {
    int i = blockIdx.x * blockDim.x + threadIdx.x;
    int per4 = (B * N) >> 2;
    if (i >= 2 * per4) return;
    int cloud = (i >= per4) ? 1 : 0;
    int i2 = i - cloud * per4;
    const float4* p4 = (const float4*)(cloud ? pc1 : pc0) + (size_t)i2 * 3;
    float4 q0 = p4[0], q1 = p4[1], q2 = p4[2];
    uint4 pkv = pk4[i];
    float xs[4] = {q0.x, q0.w, q1.z, q2.y};
    float ys[4] = {q0.y, q1.x, q1.w, q2.z};
    float zs[4] = {q0.z, q1.y, q2.x, q2.w};
    unsigned pr[4] = {pkv.x, pkv.y, pkv.z, pkv.w};
    #pragma unroll
    for (int k = 0; k < 4; ++k) {
        int o = off[pr[k] >> 8] + (int)(pr[k] & 255u);
        csr[o] = make_float4(xs[k], ys[k], zs[k], 0.0f);
    }
}

// K4: wave per 8 voxels, lane = channel, broadcast csr reads. NEW: the first
// point of all 16 lists (8 voxels x 2 clouds) is prefetched UNCONDITIONALLY
// before the compute loop (indices always valid: off[.] <= npts, csr has +4
// pad) -> MLP 16 instead of 1-2 dependent chains. 82% of non-empty bins have
// exactly 1 point, so the prefetched value IS the list in the common case;
// only n>1 bins (5.6% of voxels) take the load-loop slow path.
__global__ __launch_bounds__(256)
void gather(const float4* __restrict__ csr, const int* __restrict__ off,
            const float* __restrict__ P, float* __restrict__ out, int B) {
    int g = blockIdx.x * blockDim.x + threadIdx.x;
    int c = g & 63;
    int w = g >> 6;
    int noct = (B * NVOXD) >> 3;
    if (w >= noct) return;

    float A   = P[0*64+c], Bw  = P[1*64+c], Cw  = P[2*64+c];
    float w3s = P[3*64+c], w4s = P[4*64+c], w5s = P[5*64+c];
    float w6s = P[6*64+c], w7s = P[7*64+c], offc = P[8*64+c];
    float A1 = A - w3s, B1 = Bw - w4s, C1 = Cw - w5s;   // 1-point fast path coeffs
    int base1 = B * NVOXD;
    int bv0 = w << 3;

    int4 a0  = *(const int4*)(off + bv0);
    int4 a0b = *(const int4*)(off + bv0 + 4);
    int4 a1  = *(const int4*)(off + base1 + bv0);
    int4 a1b = *(const int4*)(off + base1 + bv0 + 4);
    int o0[9] = {a0.x, a0.y, a0.z, a0.w, a0b.x, a0b.y, a0b.z, a0b.w,
                 off[bv0 + 8]};
    int o1[9] = {a1.x, a1.y, a1.z, a1.w, a1b.x, a1b.y, a1b.z, a1b.w,
                 off[base1 + bv0 + 8]};    // sentinel off[n]=npts covers the end

    // Unconditional first-point prefetch: 16 independent loads in flight.
    float4 p0[8], p1[8];
    #pragma unroll
    for (int q = 0; q < 8; ++q) {
        p0[q] = csr[o0[q]];
        p1[q] = csr[o1[q]];
    }

    #pragma unroll
    for (int q = 0; q < 8; ++q) {
        int bv = bv0 + q;
        int s0 = o0[q], e0 = o0[q + 1];
        int s1 = o1[q], e1 = o1[q + 1];
        float res = 0.0f;
        if (e0 > s0 || e1 > s1) {            // wave-uniform branch
            int v = bv & (NVOXD - 1);
            int ix = v >> 9, iy = v & 511;
            float cx = ((float)ix + 0.5f) * VXC + XMINC;
            float cy = ((float)iy + 0.5f) * VYC + YMINC;
            float basef = offc - cx * w6s - cy * w7s;
            // cloud 0 (subtract)
            int n0 = e0 - s0;
            if (n0 == 1) {
                float4 pt = p0[q];           // prefetched
                res -= fmaxf(pt.x * A1 + pt.y * B1 + pt.z * C1 + basef, 0.0f);
            } else if (n0 > 1) {
                float sx = p0[q].x, sy = p0[q].y, sz = p0[q].z;
                for (int j = s0 + 1; j < e0; ++j) {
                    float4 pt = csr[j];
                    sx += pt.x; sy += pt.y; sz += pt.z;
                }
                float inv = 1.0f / (float)n0;
                float cbias = basef - (sx * w3s + sy * w4s + sz * w5s) * inv;
                float hsum = fmaxf(p0[q].x * A + p0[q].y * Bw + p0[q].z * Cw + cbias, 0.0f);
                for (int j = s0 + 1; j < e0; ++j) {  // L1-hot re-read (broadcast)
                    float4 pt = csr[j];
                    hsum += fmaxf(pt.x * A + pt.y * Bw + pt.z * Cw + cbias, 0.0f);
                }
                res -= hsum * inv;
            }
            // cloud 1 (add)
            int n1 = e1 - s1;
            if (n1 == 1) {
                float4 pt = p1[q];           // prefetched
                res += fmaxf(pt.x * A1 + pt.y * B1 + pt.z * C1 + basef, 0.0f);
            } else if (n1 > 1) {
                float sx = p1[q].x, sy = p1[q].y, sz = p1[q].z;
                for (int j = s1 + 1; j < e1; ++j) {
                    float4 pt = csr[j];
                    sx += pt.x; sy += pt.y; sz += pt.z;
                }
                float inv = 1.0f / (float)n1;
                float cbias = basef - (sx * w3s + sy * w4s + sz * w5s) * inv;
                float hsum = fmaxf(p1[q].x * A + p1[q].y * Bw + p1[q].z * Cw + cbias, 0.0f);
                for (int j = s1 + 1; j < e1; ++j) {
                    float4 pt = csr[j];
                    hsum += fmaxf(pt.x * A + pt.y * Bw + pt.z * Cw + cbias, 0.0f);
                }
                res += hsum * inv;
            }
        }
        __builtin_nontemporal_store(res, out + ((size_t)bv << 6) + c);
    }
}

extern "C" void kernel_launch(void* const* d_in, const int* in_sizes, int n_in,
                              void* d_out, int out_size, void* d_ws, size_t ws_size,
                              hipStream_t stream) {
    const float* pc0   = (const float*)d_in[0];
    const float* pc1   = (const float*)d_in[1];
    const float* Wm    = (const float*)d_in[2];
    const float* gamma = (const float*)d_in[3];
    const float* beta  = (const float*)d_in[4];
    const float* mean  = (const float*)d_in[5];
    const float* var   = (const float*)d_in[6];
    float* out = (float*)d_out;

    int B = out_size / (NVOXD * 64);        // = 2
    int N = in_sizes[0] / (3 * B);          // = 100000
    int npts = 2 * B * N;                   // 400000
    int n = 2 * B * NVOXD;                  // 2^20 offset entries
    int nblocks_scan = n / 1024;            // 1024

    // ws layout (16B aligned): csr | off[n+4] | aux | aux2 | pk | P
    float4* csr   = (float4*)d_ws;
    int* off      = (int*)(csr + npts + 4);
    int* aux      = off + n + 4;
    int* aux2     = aux + nblocks_scan;
    unsigned* pk  = (unsigned*)(aux2 + nblocks_scan);
    float* P      = (float*)(pk + npts);

    int nzero4 = n / 4;                      // int4s to zero
    int nzero_blocks = (nzero4 + 255) / 256;
    init_and_precompute<<<nzero_blocks + 1, 256, 0, stream>>>(
        off, nzero4, Wm, gamma, beta, mean, var, P);

    int nq = npts / 4;                       // 100000 point-quads
    int g1 = (nq + 255) / 256;
    bin_points<<<g1, 256, 0, stream>>>(pc0, pc1, off, (uint4*)pk, B, N);

    scan_block<<<nblocks_scan, 256, 0, stream>>>(off, off, aux);
    scan_block<<<1, 256, 0, stream>>>(aux, aux, aux2);
    add_bases<<<(n / 4 + 255) / 256, 256, 0, stream>>>(off, aux, n / 4, npts);

    scatter_csr<<<g1, 256, 0, stream>>>(pc0, pc1, off, (const uint4*)pk, csr, B, N);

    long long total_thr = ((long long)B * NVOXD >> 3) * 64;
    int g2 = (int)((total_thr + 255) / 256);
    gather<<<g2, 256, 0, stream>>>(csr, off, P, out, B);
}

// Round 9
// 214.434 us; speedup vs baseline: 1.1095x; 1.1095x over previous
//
#include <hip/hip_runtime.h>

#define VXC 0.2f
#define VYC 0.2f
#define XMINC -51.2f
#define YMINC -51.2f
#define GXD 512
#define GYD 512
#define NVOXD (GXD * GYD)   // 2^18
#define BN_EPS 1e-3f

// K0: zero the 4 MB count array (int4/thread, blocks [0, nzero)) and, in the
// extra last block, fold BN into the linear layer (P layout [9][64]).
__global__ void init_and_precompute(int* __restrict__ cnt, int nzero4,
                                    const float* __restrict__ W,
                                    const float* __restrict__ gamma,
                                    const float* __restrict__ beta,
                                    const float* __restrict__ mean,
                                    const float* __restrict__ var,
                                    float* __restrict__ P) {
    int nzero_blocks = (nzero4 + 255) / 256;
    if ((int)blockIdx.x < nzero_blocks) {
        int i = blockIdx.x * 256 + threadIdx.x;
        if (i < nzero4) ((int4*)cnt)[i] = make_int4(0, 0, 0, 0);
        return;
    }
    int c = threadIdx.x;
    if (c >= 64) return;
    float scale = gamma[c] * (1.0f / sqrtf(var[c] + BN_EPS));
    float w0 = W[0*64+c], w1 = W[1*64+c], w2 = W[2*64+c];
    float w3 = W[3*64+c], w4 = W[4*64+c], w5 = W[5*64+c];
    float w6 = W[6*64+c], w7 = W[7*64+c], w8 = W[8*64+c];
    P[0*64+c] = (w0 + w3 + w6) * scale;
    P[1*64+c] = (w1 + w4 + w7) * scale;
    P[2*64+c] = (w2 + w5 + w8) * scale;
    P[3*64+c] = w3 * scale;
    P[4*64+c] = w4 * scale;
    P[5*64+c] = w5 * scale;
    P[6*64+c] = w6 * scale;
    P[7*64+c] = w7 * scale;
    P[8*64+c] = beta[c] - mean[c] * scale;
}

// K1: 4 points per thread via 3x float4 loads; one scattered atomic per point;
// pack (vid, pos) into one uint; uint4 store of the 4 packed records.
__global__ void bin_points(const float* __restrict__ pc0, const float* __restrict__ pc1,
                           int* __restrict__ cnt, uint4* __restrict__ pk4,
                           int B, int N) {
    int i = blockIdx.x * blockDim.x + threadIdx.x;
    int per4 = (B * N) >> 2;                 // point-quads per cloud
    if (i >= 2 * per4) return;
    int cloud = (i >= per4) ? 1 : 0;
    int i2 = i - cloud * per4;               // quad id within cloud
    int b = i2 / (N >> 2);                   // N % 4 == 0 -> b uniform over the quad
    const float4* p4 = (const float4*)(cloud ? pc1 : pc0) + (size_t)i2 * 3;
    float4 q0 = p4[0], q1 = p4[1], q2 = p4[2];
    float xs[4] = {q0.x, q0.w, q1.z, q2.y};
    float ys[4] = {q0.y, q1.x, q1.w, q2.z};
    int vbase = (cloud * B + b) * NVOXD;
    unsigned r[4];
    #pragma unroll
    for (int k = 0; k < 4; ++k) {
        // Bit-exact with reference binning
        int ix = (int)floorf((xs[k] - XMINC) / VXC); ix = min(max(ix, 0), GXD - 1);
        int iy = (int)floorf((ys[k] - YMINC) / VYC); iy = min(max(iy, 0), GYD - 1);
        int hidx = vbase + ix * GYD + iy;
        int pos = atomicAdd(cnt + hidx, 1);
        r[k] = ((unsigned)hidx << 8) | (unsigned)pos;   // pos < 256 (lambda=0.38)
    }
    pk4[i] = make_uint4(r[0], r[1], r[2], r[3]);
}

// K2a/K2b: block-wise exclusive scan. 256 threads * int4 = 1024 elems/block.
__global__ void scan_block(const int* __restrict__ in, int* __restrict__ out,
                           int* __restrict__ bsums) {
    int tid = threadIdx.x;
    size_t base = (size_t)blockIdx.x * 1024;
    int4 v = ((const int4*)(in + base))[tid];
    int t0 = v.x, t1 = t0 + v.y, t2 = t1 + v.z, t3 = t2 + v.w;
    __shared__ int lds[256];
    lds[tid] = t3;
    __syncthreads();
    for (int d = 1; d < 256; d <<= 1) {
        int t = (tid >= d) ? lds[tid - d] : 0;
        __syncthreads();
        lds[tid] += t;
        __syncthreads();
    }
    int excl = lds[tid] - t3;
    if (tid == 255) bsums[blockIdx.x] = lds[255];
    ((int4*)(out + base))[tid] = make_int4(excl, excl + t0, excl + t1, excl + t2);
}

// K2c: add scanned block bases; write CSR sentinel off[n] = total.
__global__ void add_bases(int* __restrict__ off, const int* __restrict__ bases,
                          int n4, int total) {
    int i = blockIdx.x * blockDim.x + threadIdx.x;
    if (i >= n4) return;
    int4 v = ((int4*)off)[i];
    int b = bases[i >> 8];
    v.x += b; v.y += b; v.z += b; v.w += b;
    ((int4*)off)[i] = v;
    if (i == 0) off[n4 * 4] = total;
}

// K3: 4 points/thread; scattered plain float4 stores (no atomic) into CSR order.
__global__ void scatter_csr(const float* __restrict__ pc0, const float* __restrict__ pc1,
                            const int* __restrict__ off, const uint4* __restrict__ pk4,
                            float4* __restrict__ csr, int B, int N) {
    int i = blockIdx.x * blockDim.x + threadIdx.x;
    int per4 = (B * N) >> 2;
    if (i >= 2 * per4) return;
    int cloud = (i >= per4) ? 1 : 0;
    int i2 = i - cloud * per4;
    const float4* p4 = (const float4*)(cloud ? pc1 : pc0) + (size_t)i2 * 3;
    float4 q0 = p4[0], q1 = p4[1], q2 = p4[2];
    uint4 pkv = pk4[i];
    float xs[4] = {q0.x, q0.w, q1.z, q2.y};
    float ys[4] = {q0.y, q1.x, q1.w, q2.z};
    float zs[4] = {q0.z, q1.y, q2.x, q2.w};
    unsigned pr[4] = {pkv.x, pkv.y, pkv.z, pkv.w};
    #pragma unroll
    for (int k = 0; k < 4; ++k) {
        int o = off[pr[k] >> 8] + (int)(pr[k] & 255u);
        csr[o] = make_float4(xs[k], ys[k], zs[k], 0.0f);
    }
}

// K4: wave per 8 voxels, lane = channel. Cluster stats computed INLINE
// (no stats array): 82% of non-empty voxels have exactly 1 point, where
// cluster-mean == point and the math collapses to one FMA chain.
__global__ __launch_bounds__(256)
void gather(const float4* __restrict__ csr, const int* __restrict__ off,
            const float* __restrict__ P, float* __restrict__ out, int B) {
    int g = blockIdx.x * blockDim.x + threadIdx.x;
    int c = g & 63;
    int w = g >> 6;
    int noct = (B * NVOXD) >> 3;
    if (w >= noct) return;

    float A   = P[0*64+c], Bw  = P[1*64+c], Cw  = P[2*64+c];
    float w3s = P[3*64+c], w4s = P[4*64+c], w5s = P[5*64+c];
    float w6s = P[6*64+c], w7s = P[7*64+c], offc = P[8*64+c];
    float A1 = A - w3s, B1 = Bw - w4s, C1 = Cw - w5s;   // 1-point fast path coeffs
    int base1 = B * NVOXD;
    int bv0 = w << 3;

    int4 a0  = *(const int4*)(off + bv0);
    int4 a0b = *(const int4*)(off + bv0 + 4);
    int4 a1  = *(const int4*)(off + base1 + bv0);
    int4 a1b = *(const int4*)(off + base1 + bv0 + 4);
    int o0[9] = {a0.x, a0.y, a0.z, a0.w, a0b.x, a0b.y, a0b.z, a0b.w,
                 off[bv0 + 8]};
    int o1[9] = {a1.x, a1.y, a1.z, a1.w, a1b.x, a1b.y, a1b.z, a1b.w,
                 off[base1 + bv0 + 8]};

    #pragma unroll
    for (int q = 0; q < 8; ++q) {
        int bv = bv0 + q;
        int s0 = o0[q], e0 = o0[q + 1];
        int s1 = o1[q], e1 = o1[q + 1];
        float res = 0.0f;
        if (e0 > s0 || e1 > s1) {            // wave-uniform branch
            int v = bv & (NVOXD - 1);
            int ix = v >> 9, iy = v & 511;
            float cx = ((float)ix + 0.5f) * VXC + XMINC;
            float cy = ((float)iy + 0.5f) * VYC + YMINC;
            float basef = offc - cx * w6s - cy * w7s;
            // cloud 0 (subtract)
            int n0 = e0 - s0;
            if (n0 == 1) {
                float4 pt = csr[s0];
                res -= fmaxf(pt.x * A1 + pt.y * B1 + pt.z * C1 + basef, 0.0f);
            } else if (n0 > 1) {
                float sx = 0.0f, sy = 0.0f, sz = 0.0f;
                for (int j = s0; j < e0; ++j) {
                    float4 pt = csr[j];
                    sx += pt.x; sy += pt.y; sz += pt.z;
                }
                float inv = 1.0f / (float)n0;
                float cbias = basef - (sx * w3s + sy * w4s + sz * w5s) * inv;
                float hsum = 0.0f;
                for (int j = s0; j < e0; ++j) {      // L1-hot re-read (broadcast)
                    float4 pt = csr[j];
                    hsum += fmaxf(pt.x * A + pt.y * Bw + pt.z * Cw + cbias, 0.0f);
                }
                res -= hsum * inv;
            }
            // cloud 1 (add)
            int n1 = e1 - s1;
            if (n1 == 1) {
                float4 pt = csr[s1];
                res += fmaxf(pt.x * A1 + pt.y * B1 + pt.z * C1 + basef, 0.0f);
            } else if (n1 > 1) {
                float sx = 0.0f, sy = 0.0f, sz = 0.0f;
                for (int j = s1; j < e1; ++j) {
                    float4 pt = csr[j];
                    sx += pt.x; sy += pt.y; sz += pt.z;
                }
                float inv = 1.0f / (float)n1;
                float cbias = basef - (sx * w3s + sy * w4s + sz * w5s) * inv;
                float hsum = 0.0f;
                for (int j = s1; j < e1; ++j) {
                    float4 pt = csr[j];
                    hsum += fmaxf(pt.x * A + pt.y * Bw + pt.z * Cw + cbias, 0.0f);
                }
                res += hsum * inv;
            }
        }
        __builtin_nontemporal_store(res, out + ((size_t)bv << 6) + c);
    }
}

extern "C" void kernel_launch(void* const* d_in, const int* in_sizes, int n_in,
                              void* d_out, int out_size, void* d_ws, size_t ws_size,
                              hipStream_t stream) {
    const float* pc0   = (const float*)d_in[0];
    const float* pc1   = (const float*)d_in[1];
    const float* Wm    = (const float*)d_in[2];
    const float* gamma = (const float*)d_in[3];
    const float* beta  = (const float*)d_in[4];
    const float* mean  = (const float*)d_in[5];
    const float* var   = (const float*)d_in[6];
    float* out = (float*)d_out;

    int B = out_size / (NVOXD * 64);        // = 2
    int N = in_sizes[0] / (3 * B);          // = 100000
    int npts = 2 * B * N;                   // 400000
    int n = 2 * B * NVOXD;                  // 2^20 offset entries
    int nblocks_scan = n / 1024;            // 1024

    // ws layout (16B aligned): csr | off[n+4] | aux | aux2 | pk | P
    float4* csr   = (float4*)d_ws;
    int* off      = (int*)(csr + npts + 4);
    int* aux      = off + n + 4;
    int* aux2     = aux + nblocks_scan;
    unsigned* pk  = (unsigned*)(aux2 + nblocks_scan);
    float* P      = (float*)(pk + npts);

    int nzero4 = n / 4;                      // int4s to zero
    int nzero_blocks = (nzero4 + 255) / 256;
    init_and_precompute<<<nzero_blocks + 1, 256, 0, stream>>>(
        off, nzero4, Wm, gamma, beta, mean, var, P);

    int nq = npts / 4;                       // 100000 point-quads
    int g1 = (nq + 255) / 256;
    bin_points<<<g1, 256, 0, stream>>>(pc0, pc1, off, (uint4*)pk, B, N);

    scan_block<<<nblocks_scan, 256, 0, stream>>>(off, off, aux);
    scan_block<<<1, 256, 0, stream>>>(aux, aux, aux2);
    add_bases<<<(n / 4 + 255) / 256, 256, 0, stream>>>(off, aux, n / 4, npts);

    scatter_csr<<<g1, 256, 0, stream>>>(pc0, pc1, off, (const uint4*)pk, csr, B, N);

    long long total_thr = ((long long)B * NVOXD >> 3) * 64;
    int g2 = (int)((total_thr + 255) / 256);
    gather<<<g2, 256, 0, stream>>>(csr, off, P, out, B);
}